// Round 5
// baseline (376.166 us; speedup 1.0000x reference)
//
#include <hip/hip_runtime.h>
#include <hip/hip_bf16.h>
#include <math.h>

#define B_ 64
#define F_ 128
#define S_ 2048
#define FS_ (F_*S_)   /* 262144 */
#define M_  (B_*F_)   /* 8192 */
#define EPS_ 1e-5f

typedef __bf16 v8bf __attribute__((ext_vector_type(8)));
typedef float  v16f __attribute__((ext_vector_type(16)));

__device__ __forceinline__ unsigned short f2bf_rne(float f) {
  unsigned int u = __float_as_uint(f);
  u += 0x7FFF + ((u >> 16) & 1);
  return (unsigned short)(u >> 16);
}
__device__ __forceinline__ float b2f(unsigned short u) {
  return __uint_as_float(((unsigned int)u) << 16);
}
__device__ __forceinline__ unsigned int pack2(float a, float b) {
  return (unsigned int)f2bf_rne(a) | ((unsigned int)f2bf_rne(b) << 16);
}

__device__ __forceinline__ float gelu_exact(float x) {
  return 0.5f * x * (1.0f + erff(x * 0.70710678118654752f));
}

// ---------------- BatchNorm column stats over batch ----------------
__global__ __launch_bounds__(256) void bn_stats_k(const float* __restrict__ x,
    const float* __restrict__ gamma, const float* __restrict__ beta,
    float* __restrict__ scl, float* __restrict__ shf)
{
  int j4 = blockIdx.x * 256 + threadIdx.x;
  const float4* x4 = (const float4*)x;
  float sum[4] = {0,0,0,0}, sq[4] = {0,0,0,0};
  for (int b = 0; b < B_; b++) {
    float4 v = x4[(size_t)b * (FS_/4) + j4];
    float vv[4] = {v.x, v.y, v.z, v.w};
    #pragma unroll
    for (int i = 0; i < 4; i++) { sum[i] += vv[i]; sq[i] += vv[i]*vv[i]; }
  }
  #pragma unroll
  for (int i = 0; i < 4; i++) {
    int j = j4*4 + i;
    float mu  = sum[i] * (1.0f/B_);
    float var = sq[i] * (1.0f/B_) - mu*mu;
    float rstd = rsqrtf(var + EPS_);
    float g = gamma[j];
    scl[j] = rstd * g;
    shf[j] = beta[j] - mu * rstd * g;
  }
}

// ---------------- Fused BN-apply + hierarchical pool stats; xn -> bf16 ----------------
__global__ __launch_bounds__(256) void bnpool_k(const float* __restrict__ x,
    const float* __restrict__ scl, const float* __restrict__ shf,
    unsigned short* __restrict__ xnb, float* __restrict__ stats)
{
  int bf = blockIdx.x, t = threadIdx.x;
  int b = bf >> 7, f = bf & 127;
  const float4* xp  = (const float4*)(x   + (size_t)bf * S_);
  const float4* scp = (const float4*)(scl + (size_t)f  * S_);
  const float4* shp = (const float4*)(shf + (size_t)f  * S_);

  float xr[8];
  #pragma unroll
  for (int h = 0; h < 2; h++) {
    int i4 = t*2 + h;
    float4 v = xp[i4], sc = scp[i4], sh = shp[i4];
    xr[h*4+0] = fmaf(v.x, sc.x, sh.x);
    xr[h*4+1] = fmaf(v.y, sc.y, sh.y);
    xr[h*4+2] = fmaf(v.z, sc.z, sh.z);
    xr[h*4+3] = fmaf(v.w, sc.w, sh.w);
  }
  uint4 pk;
  pk.x = pack2(xr[0], xr[1]); pk.y = pack2(xr[2], xr[3]);
  pk.z = pack2(xr[4], xr[5]); pk.w = pack2(xr[6], xr[7]);
  ((uint4*)(xnb + (size_t)bf * S_))[t] = pk;

  float a2[4], m2[4];
  float ps2 = 0.f, pq2 = 0.f, pm2 = -INFINITY;
  #pragma unroll
  for (int j = 0; j < 4; j++) {
    a2[j] = xr[2*j] + xr[2*j+1];
    m2[j] = fmaxf(xr[2*j], xr[2*j+1]);
    float pf = 0.5f * (0.5f * a2[j] + m2[j]);
    ps2 += pf; pq2 += pf*pf; pm2 = fmaxf(pm2, pf);
  }
  float a4[2], m4[2];
  float ps1 = 0.f, pq1 = 0.f, pm1 = -INFINITY;
  #pragma unroll
  for (int j = 0; j < 2; j++) {
    a4[j] = a2[2*j] + a2[2*j+1];
    m4[j] = fmaxf(m2[2*j], m2[2*j+1]);
    float pf = 0.5f * (0.25f * a4[j] + m4[j]);
    ps1 += pf; pq1 += pf*pf; pm1 = fmaxf(pm1, pf);
  }
  float a8 = a4[0] + a4[1];
  float m8 = fmaxf(m4[0], m4[1]);
  float pf8 = 0.5f * (0.125f * a8 + m8);
  float ps0 = pf8, pq0 = pf8*pf8, pm0 = pf8;

  __shared__ float wred[12];
  int lane = t & 63, wid = t >> 6;
  float PS[3] = {ps0, ps1, ps2}, PQ[3] = {pq0, pq1, pq2}, PM[3] = {pm0, pm1, pm2};
  int   LL[3] = {256, 512, 1024};
  #pragma unroll
  for (int s = 0; s < 3; s++) {
    float vs = PS[s], vq = PQ[s], vm = PM[s];
    #pragma unroll
    for (int off = 32; off > 0; off >>= 1) {
      vs += __shfl_down(vs, off);
      vq += __shfl_down(vq, off);
      vm = fmaxf(vm, __shfl_down(vm, off));
    }
    if (lane == 0) { wred[wid*3+0] = vs; wred[wid*3+1] = vq; wred[wid*3+2] = vm; }
    __syncthreads();
    if (t == 0) {
      float S = 0.f, Q = 0.f, Mx = -INFINITY;
      #pragma unroll
      for (int i = 0; i < 4; i++) {
        S += wred[i*3+0]; Q += wred[i*3+1]; Mx = fmaxf(Mx, wred[i*3+2]);
      }
      float L = (float)LL[s];
      float mean = S / L;
      float var  = (Q - S*S/L) / (L - 1.0f);
      float* base = stats + s*(64*384) + b*384;
      base[f]       = mean;
      base[128 + f] = sqrtf(fmaxf(var, 0.0f));
      base[256 + f] = Mx;
    }
    __syncthreads();
  }
}

// ---------------- All three selector MLPs in one launch ----------------
__global__ __launch_bounds__(64) void selall_k(const float* __restrict__ stats,
    const float* w1_0, const float* b1_0, const float* w2_0, const float* b2_0,
    const float* w1_1, const float* b1_1, const float* w2_1, const float* b2_1,
    const float* w1_2, const float* b1_2, const float* w2_2, const float* b2_2,
    float* __restrict__ wsel)
{
  int s = blockIdx.y, b = blockIdx.x, j = threadIdx.x;
  const float *w1, *b1, *w2, *b2;
  if      (s == 0) { w1 = w1_0; b1 = b1_0; w2 = w2_0; b2 = b2_0; }
  else if (s == 1) { w1 = w1_1; b1 = b1_1; w2 = w2_1; b2 = b2_1; }
  else             { w1 = w1_2; b1 = b1_2; w2 = w2_2; b2 = b2_2; }
  const float* st = stats + s*(64*384) + b*384;
  float acc = b1[j];
  for (int i = 0; i < 384; i++) acc = fmaf(st[i], w1[i*64 + j], acc);
  float h = fmaxf(acc, 0.0f);
  float v = h * w2[j];
  for (int off = 32; off > 0; off >>= 1) v += __shfl_down(v, off);
  if (j == 0) wsel[s*64 + b] = 1.0f / (1.0f + expf(-(v + b2[0])));
}

// ---------------- Fused pool-recompute + combine (bf16 in) -> bf16 A matrices ----------------
__global__ __launch_bounds__(256) void combfused_k(const unsigned short* __restrict__ xnb,
    const float* __restrict__ wsel,
    unsigned short* __restrict__ o8, unsigned short* __restrict__ o4,
    unsigned short* __restrict__ o2)
{
  int bf = blockIdx.x, t = threadIdx.x, b = bf >> 7;
  float wA = wsel[b];
  float wB = wsel[64 + b];
  float wC = wsel[128 + b];
  uint4 pk = ((const uint4*)(xnb + (size_t)bf * S_))[t];
  unsigned int pw[4] = {pk.x, pk.y, pk.z, pk.w};
  float xr[8];
  #pragma unroll
  for (int h = 0; h < 4; h++) {
    xr[2*h]   = b2f((unsigned short)(pw[h] & 0xFFFF));
    xr[2*h+1] = b2f((unsigned short)(pw[h] >> 16));
  }
  float a2[4], m2[4];
  ushort4 u4o;
  unsigned short uu[4];
  #pragma unroll
  for (int j = 0; j < 4; j++) {
    a2[j] = xr[2*j] + xr[2*j+1];
    m2[j] = fmaxf(xr[2*j], xr[2*j+1]);
    uu[j] = f2bf_rne(wC * (0.5f * a2[j]) + (1.0f - wC) * m2[j]);
  }
  u4o.x = uu[0]; u4o.y = uu[1]; u4o.z = uu[2]; u4o.w = uu[3];
  ((ushort4*)(o2 + (size_t)bf * 1024))[t] = u4o;

  float a4[2], m4[2];
  ushort2 u2o;
  #pragma unroll
  for (int j = 0; j < 2; j++) {
    a4[j] = a2[2*j] + a2[2*j+1];
    m4[j] = fmaxf(m2[2*j], m2[2*j+1]);
    unsigned short uv = f2bf_rne(wB * (0.25f * a4[j]) + (1.0f - wB) * m4[j]);
    if (j == 0) u2o.x = uv; else u2o.y = uv;
  }
  ((ushort2*)(o4 + (size_t)bf * 512))[t] = u2o;

  float a8 = a4[0] + a4[1];
  float m8 = fmaxf(m4[0], m4[1]);
  o8[(size_t)bf * 256 + t] = f2bf_rne(wA * (0.125f * a8) + (1.0f - wA) * m8);
}

// ---------------- All weight transposes+cvt in one launch ----------------
__global__ __launch_bounds__(256) void wt_all_k(
    const float* w10, unsigned short* t10,
    const float* w20, unsigned short* t20,
    const float* w11, unsigned short* t11,
    const float* w21, unsigned short* t21,
    const float* w12, unsigned short* t12,
    const float* w22, unsigned short* t22)
{
  int bx = blockIdx.x;
  const float* W; unsigned short* T; int K, N, loc;
  if      (bx < 64)   { W = w10; T = t10; K = 256;  N = 256;  loc = bx; }
  else if (bx < 192)  { W = w20; T = t20; K = 256;  N = 512;  loc = bx - 64; }
  else if (bx < 448)  { W = w11; T = t11; K = 512;  N = 512;  loc = bx - 192; }
  else if (bx < 960)  { W = w21; T = t21; K = 512;  N = 1024; loc = bx - 448; }
  else if (bx < 1984) { W = w12; T = t12; K = 1024; N = 1024; loc = bx - 960; }
  else                { W = w22; T = t22; K = 1024; N = 2048; loc = bx - 1984; }
  int nx = N >> 5;
  int k0 = (loc / nx) << 5;
  int n0 = (loc % nx) << 5;
  __shared__ float tile[32][33];
  int tx = threadIdx.x & 31, ty = threadIdx.x >> 5;
  #pragma unroll
  for (int i = ty; i < 32; i += 8)
    tile[i][tx] = W[(size_t)(k0 + i) * N + n0 + tx];
  __syncthreads();
  #pragma unroll
  for (int i = ty; i < 32; i += 8)
    T[(size_t)(n0 + i) * K + k0 + tx] = f2bf_rne(tile[tx][i]);
}

// ---------------- bf16 MFMA GEMM, 32x32x16, BK=64, register-prefetch pipeline ----------
// A: [M][K] bf16 ; Wt: [N][K] bf16. Block tile TM x 128, 4 waves.
// LDS row = 128B (8 x 16B chunks); logical chunk c of row m at slot c^(m&7).
// Pipeline: global->VGPR prefetch of tile k+1 issued before compute of tile k;
// vmcnt drain lands at the ds_write AFTER compute (latency hidden), not at barrier.
// MODE 0: gelu -> bf16 ; MODE 1: + Cold(bf16) -> bf16 ; MODE 2: + Cold(bf16) -> f32
template<int MODE, int TM>
__global__ __launch_bounds__(256) void mgemm_k(
    const unsigned short* __restrict__ A,
    const unsigned short* __restrict__ Wt,
    const float* __restrict__ bias,
    const unsigned short* Cold,
    unsigned short* Obf,
    float* Of32,
    int K, int N)
{
  constexpr int MI = TM / 64;          // m-subtiles per wave (2 or 1)
  constexpr int RA = TM / 4;           // A rows staged per wave (32 or 16)
  constexpr int QA = RA / 8;           // A prefetch chunks per lane (4 or 2)
  __shared__ v8bf As8[TM * 8];
  __shared__ v8bf Bs8[128 * 8];
  const int tid  = threadIdx.x;
  const int lane = tid & 63;
  const int w    = tid >> 6;
  const int bm   = blockIdx.y * TM;
  const int bn   = blockIdx.x * 128;
  const int wm   = (w >> 1) * (TM / 2);
  const int wn   = (w & 1) * 64;

  v16f acc[MI][2];
  #pragma unroll
  for (int i = 0; i < MI; i++)
    #pragma unroll
    for (int j = 0; j < 2; j++)
      #pragma unroll
      for (int r = 0; r < 16; r++) acc[i][j][r] = 0.f;

  const int lrow = lane >> 3;                  // 0..7
  const int lchk = (lane & 7) ^ lrow;          // permuted global 16B chunk
  const unsigned short* ag = A  + (size_t)(bm + w*RA + lrow) * K + lchk * 8;
  const unsigned short* bg = Wt + (size_t)(bn + w*32 + lrow) * K + lchk * 8;
  v8bf* alw = As8 + w*RA*8 + lane;             // lane's 16B slot; +64 per 8-row group
  v8bf* blw = Bs8 + w*32*8 + lane;
  const size_t row8 = (size_t)8 * K;

  uint4 pa[QA], pb[4];
  #pragma unroll
  for (int q = 0; q < QA; q++) pa[q] = *(const uint4*)(ag + q*row8);
  #pragma unroll
  for (int q = 0; q < 4;  q++) pb[q] = *(const uint4*)(bg + q*row8);
  #pragma unroll
  for (int q = 0; q < QA; q++) alw[q*64] = *(const v8bf*)&pa[q];
  #pragma unroll
  for (int q = 0; q < 4;  q++) blw[q*64] = *(const v8bf*)&pb[q];

  const int ntile = K >> 6;
  for (int it = 0; it < ntile; it++) {
    __syncthreads();                           // staged tile visible
    const bool more = (it + 1 < ntile);
    const int k1 = (it + 1) << 6;
    if (more) {
      #pragma unroll
      for (int q = 0; q < QA; q++) pa[q] = *(const uint4*)(ag + q*row8 + k1);
      #pragma unroll
      for (int q = 0; q < 4;  q++) pb[q] = *(const uint4*)(bg + q*row8 + k1);
    }
    #pragma unroll
    for (int s = 0; s < 4; s++) {
      const int c = 2*s + (lane >> 5);
      const int slot = c ^ (lane & 7);
      v8bf af[MI], bfr[2];
      #pragma unroll
      for (int i = 0; i < MI; i++)
        af[i] = As8[(wm + i*32 + (lane & 31))*8 + slot];
      #pragma unroll
      for (int j = 0; j < 2; j++)
        bfr[j] = Bs8[(wn + j*32 + (lane & 31))*8 + slot];
      #pragma unroll
      for (int i = 0; i < MI; i++)
        #pragma unroll
        for (int j = 0; j < 2; j++)
          acc[i][j] = __builtin_amdgcn_mfma_f32_32x32x16_bf16(af[i], bfr[j], acc[i][j], 0, 0, 0);
    }
    __syncthreads();                           // all waves done reading this tile
    if (more) {
      #pragma unroll
      for (int q = 0; q < QA; q++) alw[q*64] = *(const v8bf*)&pa[q];
      #pragma unroll
      for (int q = 0; q < 4;  q++) blw[q*64] = *(const v8bf*)&pb[q];
    }
  }

  // epilogue: C/D col=lane&31, row=(reg&3)+8*(reg>>2)+4*(lane>>5)
  const int col0 = bn + wn + (lane & 31);
  const int rb0  = bm + wm + ((lane >> 5) << 2);
  #pragma unroll
  for (int j = 0; j < 2; j++) {
    int c = col0 + j*32;
    float bv = bias[c];
    #pragma unroll
    for (int i = 0; i < MI; i++) {
      #pragma unroll
      for (int r = 0; r < 16; r++) {
        int rr = rb0 + i*32 + (r & 3) + ((r >> 2) << 3);
        size_t idx = (size_t)rr * N + c;
        float t = acc[i][j][r] + bv;
        if (MODE == 0) {
          Obf[idx] = f2bf_rne(gelu_exact(t));
        } else if (MODE == 1) {
          Obf[idx] = f2bf_rne(t + b2f(Cold[idx]));
        } else {
          Of32[idx] = t + b2f(Cold[idx]);
        }
      }
    }
  }
}

// ---------------- launch ----------------
extern "C" void kernel_launch(void* const* d_in, const int* in_sizes, int n_in,
                              void* d_out, int out_size, void* d_ws, size_t ws_size,
                              hipStream_t stream)
{
  const float* x     = (const float*)d_in[0];
  const float* gamma = (const float*)d_in[1];
  const float* beta  = (const float*)d_in[2];
  float* out = (float*)d_out;
  float* ws  = (float*)d_ws;

  static const int KS[3] = {8, 4, 2};

  // ---- workspace layout (float units) ----
  size_t off = 0;
  float* scl   = ws + off; off += FS_;
  float* shf   = ws + off; off += FS_;
  float* stats = ws + off; off += 3*64*384;
  float* wsel  = ws + off; off += 256;
  unsigned short* xnb = (unsigned short*)(ws + off); off += (size_t)M_ * S_ / 2;
  unsigned short* sampb[3];
  sampb[0] = (unsigned short*)(ws + off); off += (size_t)M_ * 256 / 2;
  sampb[1] = (unsigned short*)(ws + off); off += (size_t)M_ * 512 / 2;
  sampb[2] = (unsigned short*)(ws + off); off += (size_t)M_ * 1024 / 2;
  unsigned short* hb = (unsigned short*)(ws + off); off += (size_t)M_ * 2048 / 2;
  unsigned short *wt1[3], *wt2[3];
  for (int s = 0; s < 3; s++) {
    int L = S_ / KS[s];
    wt1[s] = (unsigned short*)(ws + off); off += (size_t)L * L / 2;
    wt2[s] = (unsigned short*)(ws + off); off += (size_t)L * 2 * L / 2;
  }

  // ---- weight cvt+transpose ----
  wt_all_k<<<4032, 256, 0, stream>>>(
      (const float*)d_in[3 + 0*8 + 4], wt1[0], (const float*)d_in[3 + 0*8 + 6], wt2[0],
      (const float*)d_in[3 + 1*8 + 4], wt1[1], (const float*)d_in[3 + 1*8 + 6], wt2[1],
      (const float*)d_in[3 + 2*8 + 4], wt1[2], (const float*)d_in[3 + 2*8 + 6], wt2[2]);

  // ---- BN stats -> fused BN-apply(bf16 xn) + pool-stats -> selectors -> combine ----
  bn_stats_k<<<FS_/4/256, 256, 0, stream>>>(x, gamma, beta, scl, shf);
  bnpool_k<<<M_, 256, 0, stream>>>(x, scl, shf, xnb, stats);
  selall_k<<<dim3(64, 3), 64, 0, stream>>>(stats,
      (const float*)d_in[3+0], (const float*)d_in[4+0], (const float*)d_in[5+0], (const float*)d_in[6+0],
      (const float*)d_in[3+8], (const float*)d_in[4+8], (const float*)d_in[5+8], (const float*)d_in[6+8],
      (const float*)d_in[3+16], (const float*)d_in[4+16], (const float*)d_in[5+16], (const float*)d_in[6+16],
      wsel);
  combfused_k<<<M_, 256, 0, stream>>>(xnb, wsel, sampb[0], sampb[1], sampb[2]);

  // ---- GEMM chain (bf16 MFMA 32x32x16, register-prefetch pipeline) ----
  // s=0: L=256
  mgemm_k<0,64><<<dim3(2, 128), 256, 0, stream>>>(
      sampb[0], wt1[0], (const float*)d_in[3+0*8+5], nullptr, hb, nullptr, 256, 256);
  mgemm_k<1,64><<<dim3(4, 128), 256, 0, stream>>>(
      hb, wt2[0], (const float*)d_in[3+0*8+7], sampb[1], sampb[1], nullptr, 256, 512);
  // s=1: L=512
  mgemm_k<0,64><<<dim3(4, 128), 256, 0, stream>>>(
      sampb[1], wt1[1], (const float*)d_in[3+1*8+5], nullptr, hb, nullptr, 512, 512);
  mgemm_k<1,64><<<dim3(8, 128), 256, 0, stream>>>(
      hb, wt2[1], (const float*)d_in[3+1*8+7], sampb[2], sampb[2], nullptr, 512, 1024);
  // s=2: L=1024
  mgemm_k<0,64><<<dim3(8, 128), 256, 0, stream>>>(
      sampb[2], wt1[2], (const float*)d_in[3+2*8+5], nullptr, hb, nullptr, 1024, 1024);
  mgemm_k<2,128><<<dim3(16, 64), 256, 0, stream>>>(
      hb, wt2[2], (const float*)d_in[3+2*8+7], xnb, nullptr, out, 1024, 2048);
}